// Round 1
// baseline (463.958 us; speedup 1.0000x reference)
//
#include <hip/hip_runtime.h>
#include <hip/hip_bf16.h>
#include <math.h>

#define L_MAX 1536
#define TOPK  64
#define KMIN  9

// One block per output row i. 256 threads.
__launch_bounds__(256, 2)
__global__ void finalblock_kernel(
    const float* __restrict__ xyz,   // (B,L,3,3)
    const float* __restrict__ pair,  // (B,L,L,32)
    const float* __restrict__ node,  // (B,L,32)
    const int*   __restrict__ idxg,  // (B,L)
    const float* __restrict__ We,    // (68,32)
    const float* __restrict__ Wn,    // (32,32)
    const float* __restrict__ wg,    // (32,)
    float* __restrict__ out,         // (B,L,35)
    int B, int L)
{
    const int tid = threadIdx.x;
    const int row = blockIdx.x;
    const int b = row / L;
    const int i = row - b * L;

    __shared__ float    ca[L_MAX * 3];      // CA coords, 18 KB
    __shared__ unsigned d2b[L_MAX];         // fp32 bits of d^2 (+big on diag), 6 KB
    __shared__ float    We_s[68 * 32];      // 8.7 KB
    __shared__ float    Wn_s[32 * 32];      // 4 KB
    __shared__ float    wg_s[32];
    __shared__ float    feat[8][100];       // per-edge: pair(32) | rbf(36) | node(32)
    __shared__ int      elist[128];
    __shared__ float    red[8 * 32];
    __shared__ float    vred[8][3];
    __shared__ int      ecnt;
    __shared__ int      wsum[4];

    // ---- stage weights + CA coords ----
    for (int t = tid; t < 68 * 32; t += 256) We_s[t] = We[t];
    for (int t = tid; t < 32 * 32; t += 256) Wn_s[t] = Wn[t];
    if (tid < 32) wg_s[tid] = wg[tid];
    for (int t = tid; t < L * 3; t += 256) {
        int j = t / 3, c = t - j * 3;
        ca[t] = xyz[((size_t)(b * L + j)) * 9 + 3 + c];   // atom 1 = CA
    }
    if (tid == 0) ecnt = 0;
    __syncthreads();

    const float cix = ca[i * 3 + 0], ciy = ca[i * 3 + 1], ciz = ca[i * 3 + 2];

    // ---- all-pairs squared distances for this row ----
    for (int j = tid; j < L; j += 256) {
        float dx = ca[j * 3 + 0] - cix;
        float dy = ca[j * 3 + 1] - ciy;
        float dz = ca[j * 3 + 2] - ciz;
        float d2 = dx * dx + dy * dy + dz * dz + 1e-12f;
        if (j == i) d2 = 3.0e38f;            // exclude diagonal (ref adds 999.9)
        d2b[j] = __float_as_uint(d2);
    }
    __syncthreads();

    // ---- exact 64th-smallest via 1-bit/pass radix select on fp32 bits ----
    // (positive floats are order-isomorphic to their uint bits)
    unsigned v[6];
    unsigned char alive = 0;
    int nv = 0;
    for (int j = tid; j < L; j += 256) { v[nv] = d2b[j]; alive |= (unsigned char)(1u << nv); nv++; }

    unsigned thr = 0;
    int kk = TOPK;
    for (int bit = 31; bit >= 0; --bit) {
        int cnt = 0; unsigned char c0 = 0;
        for (int e = 0; e < nv; e++) {
            if ((alive >> e) & 1) {
                if (!((v[e] >> bit) & 1u)) { c0 |= (unsigned char)(1u << e); cnt++; }
            }
        }
        for (int off = 32; off; off >>= 1) cnt += __shfl_xor(cnt, off, 64);
        if ((tid & 63) == 0) wsum[tid >> 6] = cnt;
        __syncthreads();
        int C = wsum[0] + wsum[1] + wsum[2] + wsum[3];
        __syncthreads();
        if (C >= kk) {
            alive &= c0;                       // 64th value has this bit = 0
        } else {
            kk -= C;
            alive = (unsigned char)(alive & ~c0);
            thr |= (1u << bit);                // 64th value has this bit = 1
        }
    }
    // thr == bits of the 64th-smallest d2; mask_topk(j) <=> d2b[j] <= thr

    // ---- build edge list: top-64 OR sequence-separation < 9 ----
    const int idx_i = idxg[b * L + i];
    for (int j = tid; j < L; j += 256) {
        bool m = (d2b[j] <= thr);
        if (!m && j != i) {
            int s = idxg[b * L + j] - idx_i;
            s = s < 0 ? -s : s;
            m = (s < KMIN);
        }
        if (m) {
            int p = atomicAdd(&ecnt, 1);
            if (p < 128) elist[p] = j;
        }
    }
    __syncthreads();
    const int deg = ecnt < 128 ? ecnt : 128;

    // ---- masked edge compute: batches of 8 edges x 32 out-channels ----
    const int slot = tid >> 5;    // 0..7  edge slot
    const int o    = tid & 31;    // output channel
    float node_acc = 0.f;
    float vx = 0.f, vy = 0.f, vz = 0.f;

    for (int base = 0; base < deg; base += 8) {
        __syncthreads();  // protect feat[] from previous batch's readers
        const int eg = base + slot;

        // stage pair row + node row (coalesced 128B per edge)
        if (eg < deg) {
            int j = elist[eg];
            feat[slot][o]      = pair[((size_t)(b * L + i) * L + j) * 32 + o];
            feat[slot][68 + o] = node[((size_t)(b * L + j)) * 32 + o];
        } else {
            feat[slot][o] = 0.f;
            feat[slot][68 + o] = 0.f;
        }
        // RBF(D): 8 edges x 36 bins, cooperative
        for (int q = tid; q < 8 * 36; q += 256) {
            int sl = q / 36, r = q - sl * 36;
            int eg2 = base + sl;
            float val = 0.f;
            if (eg2 < deg) {
                float Dv = sqrtf(__uint_as_float(d2b[elist[eg2]]));
                float t = (Dv - (float)r * (20.0f / 35.0f)) * (36.0f / 20.0f);
                val = __expf(-t * t);
            }
            feat[sl][32 + r] = val;
        }
        __syncthreads();

        float acc = 0.f;
        if (eg < deg) {
            #pragma unroll
            for (int f = 0; f < 68; f++) acc = fmaf(feat[slot][f], We_s[f * 32 + o], acc);
            #pragma unroll
            for (int d = 0; d < 32; d++) acc = fmaf(feat[slot][68 + d], Wn_s[d * 32 + o], acc);
            acc = fmaxf(acc, 0.f);             // relu
        }
        node_acc += acc;

        // gate = <msg, w_gate> reduced over the 32 channels of this edge
        float g = acc * wg_s[o];
        for (int w = 16; w; w >>= 1) g += __shfl_xor(g, w, 32);
        if (o == 0 && eg < deg) {
            int j = elist[eg];
            vx += g * (ca[j * 3 + 0] - cix);
            vy += g * (ca[j * 3 + 1] - ciy);
            vz += g * (ca[j * 3 + 2] - ciz);
        }
    }

    // ---- final reductions + write ----
    red[slot * 32 + o] = node_acc;
    if (o == 0) { vred[slot][0] = vx; vred[slot][1] = vy; vred[slot][2] = vz; }
    __syncthreads();

    const float denom = (float)deg + 1e-6f;
    const size_t orow = (size_t)(b * L + i) * 35;
    if (tid < 32) {
        float s = 0.f;
        #pragma unroll
        for (int s8 = 0; s8 < 8; s8++) s += red[s8 * 32 + tid];
        out[orow + tid] = s / denom;
    } else if (tid < 35) {
        int c = tid - 32;
        float s = 0.f;
        #pragma unroll
        for (int s8 = 0; s8 < 8; s8++) s += vred[s8][c];
        out[orow + 32 + c] = s / denom;
    }
}

extern "C" void kernel_launch(void* const* d_in, const int* in_sizes, int n_in,
                              void* d_out, int out_size, void* d_ws, size_t ws_size,
                              hipStream_t stream) {
    const float* xyz  = (const float*)d_in[0];
    const float* pair = (const float*)d_in[1];
    const float* node = (const float*)d_in[2];
    const int*   idx  = (const int*)d_in[3];
    const float* We   = (const float*)d_in[4];
    const float* Wn   = (const float*)d_in[5];
    const float* wg   = (const float*)d_in[6];
    float* out = (float*)d_out;

    const int BL = in_sizes[3];                       // B*L
    const long pair_sz = (long)in_sizes[1];           // B*L*L*32
    const int L = (int)(pair_sz / ((long)BL * 32));
    const int B = BL / L;

    finalblock_kernel<<<dim3(B * L), dim3(256), 0, stream>>>(
        xyz, pair, node, idx, We, Wn, wg, out, B, L);
}

// Round 2
// 409.155 us; speedup vs baseline: 1.1339x; 1.1339x over previous
//
#include <hip/hip_runtime.h>
#include <hip/hip_bf16.h>
#include <math.h>

#define L_MAX 1536
#define TOPK  64
#define KMIN  9
#define RPB   4          // rows per block = waves per block (256 threads)
#define NV    24         // d2 values per lane (L_MAX / 64)
#define MAXE  128        // max edges per row (true bound: 64 topk + 16 seq < 128)

// One wave per output row. No __syncthreads after initial ca staging.
// NOTE: assumes blocks do not straddle a batch boundary (true when L % RPB == 0).
__launch_bounds__(256, 2)
__global__ void finalblock_kernel(
    const float* __restrict__ xyz,   // (B,L,3,3)
    const float* __restrict__ pair,  // (B,L,L,32)
    const float* __restrict__ node,  // (B,L,32)
    const int*   __restrict__ idxg,  // (B,L)
    const float* __restrict__ We,    // (68,32)
    const float* __restrict__ Wn,    // (32,32)
    const float* __restrict__ wg,    // (32,)
    float* __restrict__ out,         // (B,L,35)
    int B, int L)
{
    const int tid  = threadIdx.x;
    const int lane = tid & 63;
    const int w    = tid >> 6;                 // wave id 0..3
    const int row  = blockIdx.x * RPB + w;     // global row
    const int BL   = B * L;

    __shared__ float ca[L_MAX * 3];                       // 18 KB
    __shared__ alignas(16) float feat[RPB][2][104];       // pair|rbf|node|diff per edge-pair
    __shared__ int   elist[RPB][MAXE];
    __shared__ float ed2[RPB][MAXE];

    // ---- block-cooperative ca staging (batch of first row; blocks don't cross b) ----
    const int b0 = (blockIdx.x * RPB) / L;
    for (int t = tid; t < L * 3; t += 256) {
        int j = t / 3, c = t - j * 3;
        ca[t] = xyz[((size_t)(b0 * L + j)) * 9 + 3 + c];
    }
    __syncthreads();   // the only block barrier

    if (row >= BL) return;
    const int i = row - b0 * L;
    const int gbase = b0 * L;
    const int o = lane & 31;
    const int e2 = lane >> 5;

    const float ci0 = ca[i * 3 + 0], ci1 = ca[i * 3 + 1], ci2 = ca[i * 3 + 2];

    // ---- per-lane d2 values (24 each), kept in registers ----
    unsigned vbits[NV];
    unsigned aliveInit = 0u;
    #pragma unroll
    for (int t = 0; t < NV; ++t) {
        int j = lane + (t << 6);
        unsigned ub = 0x7F7FFFFFu;
        if (j < L) {
            float dx = ca[j * 3 + 0] - ci0;
            float dy = ca[j * 3 + 1] - ci1;
            float dz = ca[j * 3 + 2] - ci2;
            float d2 = dx * dx + dy * dy + dz * dz + 1e-12f;
            if (j == i) d2 = 3.0e38f;
            ub = __float_as_uint(d2);
            aliveInit |= (1u << t);
        }
        vbits[t] = ub;
    }

    // ---- exact 64th-smallest: ballot-based radix select, zero barriers ----
    unsigned thr = 0u;
    unsigned alive = aliveInit;
    int kk = TOPK;
    int aliveCnt = L;
    for (int bit = 30; bit >= 0; --bit) {
        unsigned c0 = 0u;
        int cnt = 0;
        #pragma unroll
        for (int t = 0; t < NV; ++t) {
            bool z = ((alive >> t) & 1u) && !((vbits[t] >> bit) & 1u);
            unsigned long long blt = __ballot((int)z);
            cnt += __popcll(blt);
            if (z) c0 |= (1u << t);
        }
        if (cnt >= kk) { alive &= c0; aliveCnt = cnt; }
        else { kk -= cnt; aliveCnt -= cnt; alive &= ~c0; thr |= (1u << bit); }
        if (aliveCnt == kk) {
            // kth smallest = max of alive set; finish exactly and stop
            unsigned mx = 0u;
            #pragma unroll
            for (int t = 0; t < NV; ++t)
                if ((alive >> t) & 1u) mx = vbits[t] > mx ? vbits[t] : mx;
            #pragma unroll
            for (int off = 32; off; off >>= 1) {
                unsigned m2 = (unsigned)__shfl_xor((int)mx, off, 64);
                mx = m2 > mx ? m2 : mx;
            }
            thr = mx;
            break;
        }
    }

    // ---- build edge list (top-64 OR |idx_i-idx_j| < 9), wave-local ----
    const int idx_i = idxg[gbase + i];
    int cnt = 0;
    #pragma unroll
    for (int t = 0; t < NV; ++t) {
        int j = lane + (t << 6);
        bool m = false;
        if (j < L) {
            m = (vbits[t] <= thr);
            if (!m && j != i) {
                int s = idxg[gbase + j] - idx_i;
                s = s < 0 ? -s : s;
                m = (s < KMIN);
            }
        }
        unsigned long long blt = __ballot((int)m);
        if (m) {
            int pos = cnt + __popcll(blt & ((1ull << lane) - 1ull));
            if (pos < MAXE) {
                elist[w][pos] = j;
                ed2[w][pos] = __uint_as_float(vbits[t]);
            }
        }
        cnt += __popcll(blt);
    }
    const int deg = cnt < MAXE ? cnt : MAXE;
    asm volatile("s_waitcnt lgkmcnt(0)" ::: "memory");
    __builtin_amdgcn_wave_barrier();

    // ---- per-lane weight column (o = lane&31) in registers ----
    float wcol[100];
    #pragma unroll
    for (int f = 0; f < 68; ++f) wcol[f] = We[f * 32 + o];
    #pragma unroll
    for (int d = 0; d < 32; ++d) wcol[68 + d] = Wn[d * 32 + o];
    const float wgo = wg[o];

    // ---- edge compute: 2 edges x 32 channels per step, reg-prefetched globals ----
    float node_acc = 0.f, vxa = 0.f, vya = 0.f, vza = 0.f;
    const int nst = (deg + 1) >> 1;

    float pv = 0.f, nv = 0.f, dvv = 0.f;
    {   // prefetch step 0
        int e = e2;
        if (e < deg) {
            int j = elist[w][e];
            pv = pair[((size_t)(gbase + i) * L + j) * 32 + o];
            nv = node[((size_t)(gbase + j)) * 32 + o];
            if (o < 3) dvv = ca[j * 3 + o] - ca[i * 3 + o];
        }
    }

    for (int s = 0; s < nst; ++s) {
        // stage current step's features into this wave's LDS slice
        feat[w][e2][o]      = pv;
        feat[w][e2][68 + o] = nv;
        if (o < 3) feat[w][e2][100 + o] = dvv;
        {   // RBF: 72 values by 64 lanes (+8 on lanes 0..7)
            int e = (lane >= 36) ? 1 : 0;
            int r = lane - e * 36;
            int eg = 2 * s + e;
            float val = 0.f;
            if (eg < deg) {
                float D = sqrtf(ed2[w][eg]);
                float tt = (D - (float)r * (20.0f / 35.0f)) * 1.8f;
                val = __expf(-tt * tt);
            }
            feat[w][e][32 + r] = val;
            if (lane < 8) {
                int r2 = lane + 28;
                int eg2 = 2 * s + 1;
                float v2 = 0.f;
                if (eg2 < deg) {
                    float D = sqrtf(ed2[w][eg2]);
                    float tt = (D - (float)r2 * (20.0f / 35.0f)) * 1.8f;
                    v2 = __expf(-tt * tt);
                }
                feat[w][1][32 + r2] = v2;
            }
        }
        asm volatile("s_waitcnt lgkmcnt(0)" ::: "memory");
        __builtin_amdgcn_wave_barrier();

        // prefetch next step while computing this one
        pv = 0.f; nv = 0.f; dvv = 0.f;
        if (s + 1 < nst) {
            int e = 2 * (s + 1) + e2;
            if (e < deg) {
                int j = elist[w][e];
                pv = pair[((size_t)(gbase + i) * L + j) * 32 + o];
                nv = node[((size_t)(gbase + j)) * 32 + o];
                if (o < 3) dvv = ca[j * 3 + o] - ca[i * 3 + o];
            }
        }

        // 100-term dot from LDS broadcast x register weights
        const float* fb = &feat[w][e2][0];
        float acc = 0.f;
        #pragma unroll
        for (int f4 = 0; f4 < 25; ++f4) {
            float4 fv = *reinterpret_cast<const float4*>(fb + f4 * 4);
            acc = fmaf(fv.x, wcol[f4 * 4 + 0], acc);
            acc = fmaf(fv.y, wcol[f4 * 4 + 1], acc);
            acc = fmaf(fv.z, wcol[f4 * 4 + 2], acc);
            acc = fmaf(fv.w, wcol[f4 * 4 + 3], acc);
        }
        acc = fmaxf(acc, 0.f);            // relu (dead edges: all-zero feat -> 0)
        node_acc += acc;

        float g = acc * wgo;              // per-lane gate partial
        float dx = fb[100], dy = fb[101], dz = fb[102];
        vxa = fmaf(g, dx, vxa);
        vya = fmaf(g, dy, vya);
        vza = fmaf(g, dz, vza);
        __builtin_amdgcn_wave_barrier();
    }

    // ---- reductions + write ----
    node_acc += __shfl_xor(node_acc, 32, 64);   // combine the two edge-halves
    #pragma unroll
    for (int off = 32; off; off >>= 1) {
        vxa += __shfl_xor(vxa, off, 64);
        vya += __shfl_xor(vya, off, 64);
        vza += __shfl_xor(vza, off, 64);
    }
    const float denom = (float)deg + 1e-6f;
    const size_t orow = (size_t)row * 35;
    if (lane < 32) out[orow + lane] = node_acc / denom;
    if (lane == 0) {
        out[orow + 32] = vxa / denom;
        out[orow + 33] = vya / denom;
        out[orow + 34] = vza / denom;
    }
}

extern "C" void kernel_launch(void* const* d_in, const int* in_sizes, int n_in,
                              void* d_out, int out_size, void* d_ws, size_t ws_size,
                              hipStream_t stream) {
    const float* xyz  = (const float*)d_in[0];
    const float* pair = (const float*)d_in[1];
    const float* node = (const float*)d_in[2];
    const int*   idx  = (const int*)d_in[3];
    const float* We   = (const float*)d_in[4];
    const float* Wn   = (const float*)d_in[5];
    const float* wg   = (const float*)d_in[6];
    float* out = (float*)d_out;

    const int BL = in_sizes[3];
    const long pair_sz = (long)in_sizes[1];
    const int L = (int)(pair_sz / ((long)BL * 32));
    const int B = BL / L;

    const int grid = (BL + RPB - 1) / RPB;
    finalblock_kernel<<<dim3(grid), dim3(256), 0, stream>>>(
        xyz, pair, node, idx, We, Wn, wg, out, B, L);
}